// Round 1
// baseline (110.441 us; speedup 1.0000x reference)
//
#include <hip/hip_runtime.h>
#include <math.h>

#define NFRAMES 64
#define NATOMS  512
#define NSEG    129795   // 509*510/2 ordered pairs with j-i>1
#define BLOCK   256

struct f3 { float x, y, z; };

__device__ __forceinline__ f3 f3sub(f3 a, f3 b) { return f3{a.x - b.x, a.y - b.y, a.z - b.z}; }
__device__ __forceinline__ f3 f3cross(f3 a, f3 b) {
    return f3{ fmaf(a.y, b.z, -a.z * b.y),
               fmaf(a.z, b.x, -a.x * b.z),
               fmaf(a.x, b.y, -a.y * b.x) };
}
__device__ __forceinline__ float f3dot(f3 a, f3 b) {
    return fmaf(a.x, b.x, fmaf(a.y, b.y, a.z * b.z));
}

__global__ __launch_bounds__(BLOCK) void writhe_kernel(
    const float* __restrict__ xyz,      // (NFRAMES, NATOMS, 3)
    const int4*  __restrict__ segs,     // (NSEG, 4)
    float*       __restrict__ out)      // (NFRAMES, NSEG)
{
    __shared__ float sp[NATOMS * 3];    // one frame, 6 KB

    const int f = blockIdx.y;
    const float* fx = xyz + (size_t)f * (NATOMS * 3);
    // stage frame into LDS (1536 floats, 256 threads -> 6 each, coalesced)
    for (int t = threadIdx.x; t < NATOMS * 3; t += BLOCK) sp[t] = fx[t];
    __syncthreads();

    const int s = blockIdx.x * BLOCK + threadIdx.x;
    if (s >= NSEG) return;

    const int4 sg = segs[s];

    f3 p1{sp[3 * sg.x], sp[3 * sg.x + 1], sp[3 * sg.x + 2]};
    f3 p2{sp[3 * sg.y], sp[3 * sg.y + 1], sp[3 * sg.y + 2]};
    f3 p3{sp[3 * sg.z], sp[3 * sg.z + 1], sp[3 * sg.z + 2]};
    f3 p4{sp[3 * sg.w], sp[3 * sg.w + 1], sp[3 * sg.w + 2]};

    f3 r12 = f3sub(p2, p1);
    f3 r13 = f3sub(p3, p1);
    f3 r14 = f3sub(p4, p1);
    f3 r23 = f3sub(p3, p2);
    f3 r24 = f3sub(p4, p2);
    f3 r34 = f3sub(p4, p3);

    f3 c1 = f3cross(r13, r14);
    f3 c2 = f3cross(r14, r24);
    f3 c3 = f3cross(r24, r23);
    f3 c4 = f3cross(r23, r13);

    float in1 = rsqrtf(f3dot(c1, c1));
    float in2 = rsqrtf(f3dot(c2, c2));
    float in3 = rsqrtf(f3dot(c3, c3));
    float in4 = rsqrtf(f3dot(c4, c4));

    float d12 = fminf(fmaxf(f3dot(c1, c2) * (in1 * in2), -1.0f), 1.0f);
    float d23 = fminf(fmaxf(f3dot(c2, c3) * (in2 * in3), -1.0f), 1.0f);
    float d34 = fminf(fmaxf(f3dot(c3, c4) * (in3 * in4), -1.0f), 1.0f);
    float d41 = fminf(fmaxf(f3dot(c4, c1) * (in4 * in1), -1.0f), 1.0f);

    float theta = asinf(d12) + asinf(d23) + asinf(d34) + asinf(d41);

    float sv  = f3dot(f3cross(r34, r12), r13);
    float sgn = (sv > 0.0f) ? 1.0f : ((sv < 0.0f) ? -1.0f : 0.0f);

    out[(size_t)f * NSEG + s] = theta * sgn * 0.15915494309189535f; // 1/(2*pi)
}

extern "C" void kernel_launch(void* const* d_in, const int* in_sizes, int n_in,
                              void* d_out, int out_size, void* d_ws, size_t ws_size,
                              hipStream_t stream) {
    const float* xyz  = (const float*)d_in[0];
    const int4*  segs = (const int4*)d_in[1];
    float*       out  = (float*)d_out;

    dim3 grid((NSEG + BLOCK - 1) / BLOCK, NFRAMES);
    writhe_kernel<<<grid, BLOCK, 0, stream>>>(xyz, segs, out);
}

// Round 2
// 95.615 us; speedup vs baseline: 1.1551x; 1.1551x over previous
//
#include <hip/hip_runtime.h>
#include <math.h>

#define NFRAMES 64
#define NATOMS  512
#define NSEG    129795   // pairs (i,j), i in [0,509), j-i>1
#define BLOCK   256

struct f3 { float x, y, z; };

__device__ __forceinline__ f3 f3sub(f3 a, f3 b) { return f3{a.x - b.x, a.y - b.y, a.z - b.z}; }
__device__ __forceinline__ f3 f3cross(f3 a, f3 b) {
    return f3{ fmaf(a.y, b.z, -a.z * b.y),
               fmaf(a.z, b.x, -a.x * b.z),
               fmaf(a.x, b.y, -a.y * b.x) };
}
__device__ __forceinline__ float f3dot(f3 a, f3 b) {
    return fmaf(a.x, b.x, fmaf(a.y, b.y, a.z * b.z));
}

__device__ __forceinline__ float fsqrt_raw(float x) {
#if __has_builtin(__builtin_amdgcn_sqrtf)
    return __builtin_amdgcn_sqrtf(x);   // single v_sqrt_f32, no fixup
#else
    return sqrtf(x);
#endif
}
__device__ __forceinline__ float frsq_raw(float x) {
#if __has_builtin(__builtin_amdgcn_rsqf)
    return __builtin_amdgcn_rsqf(x);    // single v_rsq_f32, no fixup
#else
    return rsqrtf(x);
#endif
}

// Abramowitz & Stegun 4.4.45: |err| <= 5e-5 rad on [-1,1], branchless.
__device__ __forceinline__ float fast_asin(float x) {
    float ax = fminf(fabsf(x), 1.0f);   // clamp folds the jnp.clip too
    float p  = fmaf(ax, fmaf(ax, fmaf(ax, -0.0187293f, 0.0742610f), -0.2121144f), 1.5707288f);
    float r  = 1.57079632679f - fsqrt_raw(1.0f - ax) * p;
    return copysignf(r, x);
}

__global__ __launch_bounds__(BLOCK) void writhe_kernel(
    const float* __restrict__ xyz,      // (NFRAMES, NATOMS, 3)
    const int4*  __restrict__ segs,     // (NSEG, 4)
    float*       __restrict__ out)      // (NFRAMES, NSEG)
{
    __shared__ float4 sp[NATOMS];       // padded to 16B -> ds_read_b128, 8 KB

    const int f = blockIdx.y;
    const float* fx = xyz + (size_t)f * (NATOMS * 3);
    // stage frame: each lane reads 12B contiguous (merges to dwordx3, coalesced)
    for (int a = threadIdx.x; a < NATOMS; a += BLOCK) {
        const float* g = fx + 3 * a;
        sp[a] = make_float4(g[0], g[1], g[2], 0.0f);
    }
    __syncthreads();

    const int s = blockIdx.x * BLOCK + threadIdx.x;
    if (s >= NSEG) return;

    const int4 sg = segs[s];

    float4 q1 = sp[sg.x];
    float4 q2 = sp[sg.y];
    float4 q3 = sp[sg.z];
    float4 q4 = sp[sg.w];
    f3 p1{q1.x, q1.y, q1.z};
    f3 p2{q2.x, q2.y, q2.z};
    f3 p3{q3.x, q3.y, q3.z};
    f3 p4{q4.x, q4.y, q4.z};

    f3 r12 = f3sub(p2, p1);
    f3 r13 = f3sub(p3, p1);
    f3 r14 = f3sub(p4, p1);
    f3 r23 = f3sub(p3, p2);
    f3 r24 = f3sub(p4, p2);
    f3 r34 = f3sub(p4, p3);

    f3 c1 = f3cross(r13, r14);
    f3 c2 = f3cross(r14, r24);
    f3 c3 = f3cross(r24, r23);
    f3 c4 = f3cross(r23, r13);

    float in1 = frsq_raw(f3dot(c1, c1));
    float in2 = frsq_raw(f3dot(c2, c2));
    float in3 = frsq_raw(f3dot(c3, c3));
    float in4 = frsq_raw(f3dot(c4, c4));

    float d12 = f3dot(c1, c2) * (in1 * in2);
    float d23 = f3dot(c2, c3) * (in2 * in3);
    float d34 = f3dot(c3, c4) * (in3 * in4);
    float d41 = f3dot(c4, c1) * (in4 * in1);

    float theta = fast_asin(d12) + fast_asin(d23) + fast_asin(d34) + fast_asin(d41);

    float sv  = f3dot(f3cross(r34, r12), r13);
    float sgn = (sv > 0.0f) ? 1.0f : ((sv < 0.0f) ? -1.0f : 0.0f);

    out[(size_t)f * NSEG + s] = theta * sgn * 0.15915494309189535f; // 1/(2*pi)
}

extern "C" void kernel_launch(void* const* d_in, const int* in_sizes, int n_in,
                              void* d_out, int out_size, void* d_ws, size_t ws_size,
                              hipStream_t stream) {
    const float* xyz  = (const float*)d_in[0];
    const int4*  segs = (const int4*)d_in[1];
    float*       out  = (float*)d_out;

    dim3 grid((NSEG + BLOCK - 1) / BLOCK, NFRAMES);
    writhe_kernel<<<grid, BLOCK, 0, stream>>>(xyz, segs, out);
}

// Round 4
// 90.511 us; speedup vs baseline: 1.2202x; 1.0564x over previous
//
#include <hip/hip_runtime.h>
#include <math.h>

#define NFRAMES 64
#define NATOMS  512
#define NSEG    129795            // pairs (i,j), j-i>1, 509*510/2
#define NPAIR2  ((NSEG + 1) / 2)  // threads per frame, 2 pairs each
#define BLOCK   256

typedef float v2 __attribute__((ext_vector_type(2)));

__device__ __forceinline__ v2 v2s(float x) { v2 r; r.x = x; r.y = x; return r; }
__device__ __forceinline__ v2 vfma(v2 a, v2 b, v2 c) { return __builtin_elementwise_fma(a, b, c); }

__device__ __forceinline__ v2 vabs(v2 x) {
    v2 r; r.x = fabsf(x.x); r.y = fabsf(x.y); return r;
}
__device__ __forceinline__ v2 vmin1(v2 a) {
    v2 r; r.x = fminf(a.x, 1.0f); r.y = fminf(a.y, 1.0f); return r;
}
__device__ __forceinline__ v2 vsqrt_raw(v2 x) {
    v2 r;
    r.x = __builtin_amdgcn_sqrtf(x.x);
    r.y = __builtin_amdgcn_sqrtf(x.y);
    return r;
}
__device__ __forceinline__ v2 vrsq_raw(v2 x) {
    v2 r;
    r.x = __builtin_amdgcn_rsqf(x.x);
    r.y = __builtin_amdgcn_rsqf(x.y);
    return r;
}
__device__ __forceinline__ v2 vcopysign(v2 m, v2 s) {
    v2 r; r.x = copysignf(m.x, s.x); r.y = copysignf(m.y, s.y); return r;
}

// A&S 4.4.45, |err| <= 5e-5 rad, branchless; clamp folds jnp.clip.
__device__ __forceinline__ v2 vasin(v2 x) {
    v2 ax = vmin1(vabs(x));
    v2 p  = vfma(ax, vfma(ax, vfma(ax, v2s(-0.0187293f), v2s(0.0742610f)), v2s(-0.2121144f)), v2s(1.5707288f));
    v2 r  = v2s(1.57079632679f) - vsqrt_raw(v2s(1.0f) - ax) * p;
    return vcopysign(r, x);
}

struct v23 { v2 x, y, z; };  // two 3-vectors (pair0, pair1), SoA across the v2 lanes

__device__ __forceinline__ v23 vsub(v23 a, v23 b) { return v23{a.x - b.x, a.y - b.y, a.z - b.z}; }
__device__ __forceinline__ v23 vcross(v23 a, v23 b) {
    return v23{ vfma(a.y, b.z, -(a.z * b.y)),
                vfma(a.z, b.x, -(a.x * b.z)),
                vfma(a.x, b.y, -(a.y * b.x)) };
}
__device__ __forceinline__ v2 vdot(v23 a, v23 b) {
    return vfma(a.x, b.x, vfma(a.y, b.y, a.z * b.z));
}

__global__ __launch_bounds__(BLOCK) void writhe_kernel(
    const float* __restrict__ xyz,      // (NFRAMES, NATOMS, 3)
    const int4*  __restrict__ segs,     // (NSEG, 4)
    float*       __restrict__ out)      // (NFRAMES, NSEG)
{
    __shared__ float4 sp[NATOMS];       // 8 KB

    const int f = blockIdx.y;
    const float* fx = xyz + (size_t)f * (NATOMS * 3);
    for (int a = threadIdx.x; a < NATOMS; a += BLOCK) {
        const float* g = fx + 3 * a;
        sp[a] = make_float4(g[0], g[1], g[2], 0.0f);
    }
    __syncthreads();

    const int t  = blockIdx.x * BLOCK + threadIdx.x;
    const int s0 = 2 * t;
    if (s0 >= NSEG) return;
    const int s1 = (s0 + 1 < NSEG) ? (s0 + 1) : s0;  // clamp; store guarded

    const int4 g0 = segs[s0];
    const int4 g1 = segs[s1];

    float4 a1 = sp[g0.x], a2 = sp[g0.y], a3 = sp[g0.z], a4 = sp[g0.w];
    float4 b1 = sp[g1.x], b2 = sp[g1.y], b3 = sp[g1.z], b4 = sp[g1.w];

    v23 p1{{a1.x, b1.x}, {a1.y, b1.y}, {a1.z, b1.z}};
    v23 p2{{a2.x, b2.x}, {a2.y, b2.y}, {a2.z, b2.z}};
    v23 p3{{a3.x, b3.x}, {a3.y, b3.y}, {a3.z, b3.z}};
    v23 p4{{a4.x, b4.x}, {a4.y, b4.y}, {a4.z, b4.z}};

    // Exact reference op structure: all r's, all crosses, all dots direct.
    v23 r12 = vsub(p2, p1);
    v23 r13 = vsub(p3, p1);
    v23 r14 = vsub(p4, p1);
    v23 r23 = vsub(p3, p2);
    v23 r24 = vsub(p4, p2);
    v23 r34 = vsub(p4, p3);

    v23 c1 = vcross(r13, r14);
    v23 c2 = vcross(r14, r24);
    v23 c3 = vcross(r24, r23);
    v23 c4 = vcross(r23, r13);

    v2 in1 = vrsq_raw(vdot(c1, c1));
    v2 in2 = vrsq_raw(vdot(c2, c2));
    v2 in3 = vrsq_raw(vdot(c3, c3));
    v2 in4 = vrsq_raw(vdot(c4, c4));

    v2 d12 = vdot(c1, c2) * (in1 * in2);
    v2 d23 = vdot(c2, c3) * (in2 * in3);
    v2 d34 = vdot(c3, c4) * (in3 * in4);
    v2 d41 = vdot(c4, c1) * (in4 * in1);

    v2 theta = (vasin(d12) + vasin(d23)) + (vasin(d34) + vasin(d41));

    v2 sv = vdot(vcross(r34, r12), r13);

    float w0 = theta.x * ((sv.x > 0.0f) ? 1.0f : ((sv.x < 0.0f) ? -1.0f : 0.0f)) * 0.15915494309189535f;
    float w1 = theta.y * ((sv.y > 0.0f) ? 1.0f : ((sv.y < 0.0f) ? -1.0f : 0.0f)) * 0.15915494309189535f;

    const size_t base = (size_t)f * NSEG;
    out[base + s0] = w0;
    if (s0 + 1 < NSEG) out[base + s0 + 1] = w1;
}

extern "C" void kernel_launch(void* const* d_in, const int* in_sizes, int n_in,
                              void* d_out, int out_size, void* d_ws, size_t ws_size,
                              hipStream_t stream) {
    const float* xyz  = (const float*)d_in[0];
    const int4*  segs = (const int4*)d_in[1];
    float*       out  = (float*)d_out;

    dim3 grid((NPAIR2 + BLOCK - 1) / BLOCK, NFRAMES);
    writhe_kernel<<<grid, BLOCK, 0, stream>>>(xyz, segs, out);
}